// Round 1
// baseline (471.552 us; speedup 1.0000x reference)
//
#include <hip/hip_runtime.h>
#include <hip/hip_bf16.h>

typedef _Float16 h8 __attribute__((ext_vector_type(8)));
typedef __bf16   b8 __attribute__((ext_vector_type(8)));
typedef float    f4 __attribute__((ext_vector_type(4)));

#define B_    4
#define S_    4096
#define D_    512
#define ROWS_ (B_ * S_)          // 16384
#define NQKV_ 1536
#define BR    32                 // q-rows per block
#define BC    32                 // keys per iteration
#define KP    520                // K LDS pitch (f16)
#define PP    40                 // P LDS pitch (bf16)
#define NIT   (S_ / BC)          // 128
#define MSH   (30.0f * 1.4426950408889634f)   // fixed softmax shift (log2 units)
#define L2E   1.4426950408889634f

// async global->LDS, 16B per lane; dst is wave-uniform base (+lane*16 implied)
__device__ __forceinline__ void gl_lds16(const void* src, void* dst) {
    __builtin_amdgcn_global_load_lds(
        (const __attribute__((address_space(1))) unsigned int*)src,
        (__attribute__((address_space(3))) unsigned int*)dst, 16, 0, 0);
}

// ---------------------------------------------------------------- convert ---
__global__ __launch_bounds__(256) void convert_all(
    const float* __restrict__ x,
    const float* __restrict__ Wq, const float* __restrict__ Wk, const float* __restrict__ Wv,
    const float* __restrict__ bq, const float* __restrict__ bk, const float* __restrict__ bv,
    const float* __restrict__ Wo,
    _Float16* __restrict__ xh, _Float16* __restrict__ wqkvT, _Float16* __restrict__ woT,
    float* __restrict__ bqkv)
{
    long i0 = (long)blockIdx.x * blockDim.x + threadIdx.x;
    long stride = (long)gridDim.x * blockDim.x;
    const long NX  = (long)ROWS_ * D_;
    const long NW  = (long)D_ * NQKV_;
    const long NWO = (long)D_ * D_;

    for (long i = i0; i < NX; i += stride) xh[i] = (_Float16)x[i];

    for (long i = i0; i < NW; i += stride) {
        long n = i >> 9, k = i & 511;
        long which = n >> 9, nn = n & 511;
        const float* W = (which == 0) ? Wq : (which == 1) ? Wk : Wv;
        wqkvT[i] = (_Float16)W[k * 512 + nn];
    }
    for (long i = i0; i < NWO; i += stride) {
        long n = i >> 9, k = i & 511;
        woT[i] = (_Float16)Wo[k * 512 + n];
    }
    for (long i = i0; i < NQKV_; i += stride) {
        long which = i >> 9, nn = i & 511;
        const float* bb = (which == 0) ? bq : (which == 1) ? bk : bv;
        bqkv[i] = bb[nn];
    }
}

// ------------------------------------------------------------------- GEMM ---
#define GP 40
template <bool OUT_F16>
__global__ __launch_bounds__(256) void gemm_bt(
    const _Float16* __restrict__ A, const _Float16* __restrict__ BT,
    const float* __restrict__ bias, void* __restrict__ Cout,
    int M, int N, int K)
{
    __shared__ _Float16 As[128 * GP];
    __shared__ _Float16 Bs[128 * GP];

    int tid = threadIdx.x;
    int w = tid >> 6, lane = tid & 63, quad = lane >> 4, l16 = lane & 15;
    long row0 = (long)blockIdx.x * 128, col0 = (long)blockIdx.y * 128;
    int wr = (w >> 1) * 64, wc = (w & 1) * 64;

    f4 acc[4][4];
    for (int i = 0; i < 4; i++)
        for (int j = 0; j < 4; j++) acc[i][j] = (f4){0.f, 0.f, 0.f, 0.f};

    int sr = tid >> 1, sc = (tid & 1) * 16;
    for (int k0 = 0; k0 < K; k0 += 32) {
        __syncthreads();
        {
            const h8* ga = (const h8*)(A  + (row0 + sr) * K + k0 + sc);
            const h8* gb = (const h8*)(BT + (col0 + sr) * K + k0 + sc);
            *(h8*)(As + sr * GP + sc)     = ga[0];
            *(h8*)(As + sr * GP + sc + 8) = ga[1];
            *(h8*)(Bs + sr * GP + sc)     = gb[0];
            *(h8*)(Bs + sr * GP + sc + 8) = gb[1];
        }
        __syncthreads();
        h8 af[4], bf[4];
        for (int i = 0; i < 4; i++) af[i] = *(const h8*)(As + (wr + i * 16 + l16) * GP + quad * 8);
        for (int j = 0; j < 4; j++) bf[j] = *(const h8*)(Bs + (wc + j * 16 + l16) * GP + quad * 8);
        for (int i = 0; i < 4; i++)
            for (int j = 0; j < 4; j++)
                acc[i][j] = __builtin_amdgcn_mfma_f32_16x16x32_f16(af[i], bf[j], acc[i][j], 0, 0, 0);
    }
    for (int i = 0; i < 4; i++)
        for (int j = 0; j < 4; j++)
            for (int r = 0; r < 4; r++) {
                long row = row0 + wr + i * 16 + quad * 4 + r;
                long col = col0 + wc + j * 16 + l16;
                float v = acc[i][j][r] + bias[col];
                if (OUT_F16) ((_Float16*)Cout)[row * N + col] = (_Float16)v;
                else         ((float*)Cout)[row * N + col]    = v;
            }
}

// ------------------------------------------------------------ V transpose ---
// vT[b][d][s] = (bf16) qkv[b*4096+s][1024+d]
__global__ __launch_bounds__(256) void transpose_v(const _Float16* __restrict__ qkv,
                                                   __bf16* __restrict__ vT)
{
    __shared__ float tile[32][33];
    int b = blockIdx.z;
    int s0 = blockIdx.x * 32, h0 = blockIdx.y * 32;
    int x = threadIdx.x & 31, y = threadIdx.x >> 5;
    for (int i = 0; i < 4; i++) {
        int s = s0 + y + i * 8;
        tile[y + i * 8][x] = (float)qkv[((long)b * S_ + s) * NQKV_ + 1024 + h0 + x];
    }
    __syncthreads();
    for (int i = 0; i < 4; i++) {
        int h = h0 + y + i * 8;
        vT[((long)b * D_ + h) * S_ + s0 + x] = (__bf16)tile[x][y + i * 8];
    }
}

// -------------------------------------------------------- flash attention ---
// BR=32 rows/block, BC=32 keys/iter, 4 waves, 512 blocks (2/CU).
// Fixed-shift softmax (no running max): P = exp2(S*L2E - MSH), P in bf16,
// l accumulated per-lane, reduced once at the end.
// Wave w: scores for row strip (w&1)*16, key half (w>>1)*16 (16x16 tile);
//         PV for d-cols w*128..w*128+127 across all 32 rows.
// V fragments are loaded DIRECTLY from global vT into registers (the b8 at
// vT[b][d][kt*32+quad*8] is exactly the PV B-operand fragment) -- no LDS
// round-trip for V. Double-buffered one iteration ahead.
__global__ __launch_bounds__(256, 2) void attn_kernel(const _Float16* __restrict__ qkv,
                                                      const __bf16* __restrict__ vT,
                                                      _Float16* __restrict__ yb)
{
    __shared__ _Float16 Ks[BC * KP];        // 33280 B
    __shared__ __bf16   Ps[BR * PP];        // 2560 B
    __shared__ float    lpart[2][BR];       // 256 B

    const int tid = threadIdx.x;
    const int w = tid >> 6, lane = tid & 63, quad = lane >> 4, l16 = lane & 15;
    const int rs = (w & 1) * 16;            // score row strip
    const int kh = w >> 1;                  // key half (0/1)
    const int b = blockIdx.y;
    const long q0 = (long)blockIdx.x * BR;
    const long rowBase = (long)b * S_;

    // ---- K DMA for kt=0: wave w stages key rows w*8..w*8+7
    const _Float16* kbase = qkv + rowBase * NQKV_ + 512;
    for (int i = 0; i < 8; i++) {
        int r = w * 8 + i;
        gl_lds16(kbase + (long)r * NQKV_ + lane * 8, Ks + r * KP);
    }

    // ---- V fragments for kt=0, straight from global in MFMA-B layout:
    // lane (quad,l16), frag ct: d = w*128 + ct*16 + l16, keys quad*8..+7
    const __bf16* vbase = vT + ((long)b * D_ + w * 128 + l16) * S_ + quad * 8;
    b8 vcur[8], vnxt[8];
#pragma unroll
    for (int ct = 0; ct < 8; ct++)
        vcur[ct] = *(const b8*)(vbase + (long)ct * 16 * S_);

    // ---- Q fragments: row q0 + rs + l16, all 512 k
    h8 Qf[16];
    {
        const _Float16* qrow = qkv + (rowBase + q0 + rs + l16) * NQKV_;
#pragma unroll
        for (int ks = 0; ks < 16; ks++)
            Qf[ks] = *(const h8*)(qrow + ks * 32 + quad * 8);
    }

    f4 O[2][8];
#pragma unroll
    for (int rt = 0; rt < 2; rt++)
#pragma unroll
        for (int ct = 0; ct < 8; ct++) O[rt][ct] = (f4){0.f, 0.f, 0.f, 0.f};
    float lo[4] = {0.f, 0.f, 0.f, 0.f};

    __syncthreads();   // kt=0 K DMA drained (syncthreads waits vmcnt) + visible

    for (int kt = 0; kt < NIT; kt++) {
        // ---- scores: 16x16 tile (rows rs, keys kh*16), K=512 from regs x LDS
        f4 S = (f4){0.f, 0.f, 0.f, 0.f};
#pragma unroll
        for (int ks = 0; ks < 16; ks++) {
            h8 kb = *(const h8*)(Ks + (kh * 16 + l16) * KP + ks * 32 + quad * 8);
            S = __builtin_amdgcn_mfma_f32_16x16x32_f16(Qf[ks], kb, S, 0, 0, 0);
        }
        // ---- fixed-shift exp; accumulate l from the bf16-rounded P
#pragma unroll
        for (int r = 0; r < 4; r++) {
            float p = exp2f(S[r] * L2E - MSH);
            __bf16 pb = (__bf16)p;
            Ps[(rs + quad * 4 + r) * PP + kh * 16 + l16] = pb;
            lo[r] += (float)pb;
        }
        __syncthreads();   // B: Ps visible; all Ks score-reads done

        // prefetch next tile: K via DMA (Ks free after barrier B), V into regs
        if (kt + 1 < NIT) {
            const _Float16* kn = qkv + (rowBase + (long)(kt + 1) * BC) * NQKV_ + 512;
#pragma unroll
            for (int i = 0; i < 8; i++) {
                int r = w * 8 + i;
                gl_lds16(kn + (long)r * NQKV_ + lane * 8, Ks + r * KP);
            }
            const __bf16* vn = vbase + (long)(kt + 1) * BC;
#pragma unroll
            for (int ct = 0; ct < 8; ct++)
                vnxt[ct] = *(const b8*)(vn + (long)ct * 16 * S_);
        }

        // ---- PV: A = P rows rt*16+l16 (K=32) from LDS, B = V frags from regs
        b8 pa[2];
#pragma unroll
        for (int rt = 0; rt < 2; rt++)
            pa[rt] = *(const b8*)(Ps + (rt * 16 + l16) * PP + quad * 8);
#pragma unroll
        for (int ct = 0; ct < 8; ct++)
#pragma unroll
            for (int rt = 0; rt < 2; rt++)
                O[rt][ct] = __builtin_amdgcn_mfma_f32_16x16x32_bf16(pa[rt], vcur[ct], O[rt][ct], 0, 0, 0);

        __syncthreads();   // C: Ps reads done; K DMA + vnxt loads drained

#pragma unroll
        for (int ct = 0; ct < 8; ct++) vcur[ct] = vnxt[ct];
    }

    // ---- epilogue: reduce l over the 16 key-columns, publish per half
#pragma unroll
    for (int r = 0; r < 4; r++)
#pragma unroll
        for (int m = 1; m < 16; m <<= 1) lo[r] += __shfl_xor(lo[r], m, 16);
    if (l16 == 0)
        for (int r = 0; r < 4; r++) lpart[kh][rs + quad * 4 + r] = lo[r];
    __syncthreads();

    for (int rt = 0; rt < 2; rt++) {
        f4 l0 = *(const f4*)(&lpart[0][rt * 16 + quad * 4]);
        f4 l1 = *(const f4*)(&lpart[1][rt * 16 + quad * 4]);
        float li[4];
        for (int r = 0; r < 4; r++) li[r] = 1.f / (l0[r] + l1[r]);
        for (int ct = 0; ct < 8; ct++)
            for (int r = 0; r < 4; r++) {
                long row = rowBase + q0 + rt * 16 + quad * 4 + r;
                long col = w * 128 + ct * 16 + l16;
                yb[row * 512 + col] = (_Float16)(O[rt][ct][r] * li[r]);
            }
    }
}

// ----------------------------------------------------------------- launch ---
extern "C" void kernel_launch(void* const* d_in, const int* in_sizes, int n_in,
                              void* d_out, int out_size, void* d_ws, size_t ws_size,
                              hipStream_t stream)
{
    const float* x  = (const float*)d_in[0];
    const float* Wq = (const float*)d_in[1];
    const float* bq = (const float*)d_in[2];
    const float* Wk = (const float*)d_in[3];
    const float* bk = (const float*)d_in[4];
    const float* Wv = (const float*)d_in[5];
    const float* bv = (const float*)d_in[6];
    const float* Wo = (const float*)d_in[7];
    const float* bo = (const float*)d_in[8];
    float* out = (float*)d_out;

    char* ws = (char*)d_ws;
    _Float16* xh    = (_Float16*)(ws);                  // 16 MB
    _Float16* qkv   = (_Float16*)(ws + 16777216);       // 48 MB  [16384][1536]
    __bf16*   vT    = (__bf16*)(ws + 67108864);         // 16 MB  [4][512][4096]
    _Float16* yb    = (_Float16*)(ws + 83886080);       // 16 MB  [16384][512]
    _Float16* wqkvT = (_Float16*)(ws + 100663296);      // 1.5 MB
    _Float16* woT   = (_Float16*)(ws + 102236160);      // 0.5 MB
    float*    bqkv  = (float*)(ws + 102760448);         // 6 KB

    convert_all<<<2048, 256, 0, stream>>>(x, Wq, Wk, Wv, bq, bk, bv, Wo,
                                          xh, wqkvT, woT, bqkv);

    dim3 g1(128, 12);
    gemm_bt<true><<<g1, 256, 0, stream>>>(xh, wqkvT, bqkv, qkv, ROWS_, NQKV_, D_);

    dim3 gt(128, 16, 4);
    transpose_v<<<gt, 256, 0, stream>>>(qkv, vT);

    dim3 ga(128, 4);
    attn_kernel<<<ga, 256, 0, stream>>>(qkv, vT, yb);

    dim3 g2(128, 4);
    gemm_bt<false><<<g2, 256, 0, stream>>>(yb, woT, bo, out, ROWS_, D_, D_);
}

// Round 2
// 457.509 us; speedup vs baseline: 1.0307x; 1.0307x over previous
//
#include <hip/hip_runtime.h>
#include <hip/hip_bf16.h>

typedef _Float16 h8 __attribute__((ext_vector_type(8)));
typedef __bf16   b8 __attribute__((ext_vector_type(8)));
typedef float    f4 __attribute__((ext_vector_type(4)));

#define B_    4
#define S_    4096
#define D_    512
#define ROWS_ (B_ * S_)          // 16384
#define NQKV_ 1536
#define BR    32                 // q-rows per block
#define BC    32                 // keys per iteration
#define KP    520                // K LDS pitch (f16)
#define PP    40                 // P LDS pitch (bf16)
#define NIT   (S_ / BC)          // 128
#define MSH   (30.0f * 1.4426950408889634f)   // fixed softmax shift (log2 units)
#define L2E   1.4426950408889634f

// async global->LDS, 16B per lane; dst is wave-uniform base (+lane*16 implied)
__device__ __forceinline__ void gl_lds16(const void* src, void* dst) {
    __builtin_amdgcn_global_load_lds(
        (const __attribute__((address_space(1))) unsigned int*)src,
        (__attribute__((address_space(3))) unsigned int*)dst, 16, 0, 0);
}

// ---------------------------------------------------------------- convert ---
__global__ __launch_bounds__(256) void convert_all(
    const float* __restrict__ x,
    const float* __restrict__ Wq, const float* __restrict__ Wk, const float* __restrict__ Wv,
    const float* __restrict__ bq, const float* __restrict__ bk, const float* __restrict__ bv,
    const float* __restrict__ Wo,
    _Float16* __restrict__ xh, _Float16* __restrict__ wqkvT, _Float16* __restrict__ woT,
    float* __restrict__ bqkv)
{
    long i0 = (long)blockIdx.x * blockDim.x + threadIdx.x;
    long stride = (long)gridDim.x * blockDim.x;
    const long NX  = (long)ROWS_ * D_;
    const long NW  = (long)D_ * NQKV_;
    const long NWO = (long)D_ * D_;

    for (long i = i0; i < NX; i += stride) xh[i] = (_Float16)x[i];

    for (long i = i0; i < NW; i += stride) {
        long n = i >> 9, k = i & 511;
        long which = n >> 9, nn = n & 511;
        const float* W = (which == 0) ? Wq : (which == 1) ? Wk : Wv;
        wqkvT[i] = (_Float16)W[k * 512 + nn];
    }
    for (long i = i0; i < NWO; i += stride) {
        long n = i >> 9, k = i & 511;
        woT[i] = (_Float16)Wo[k * 512 + n];
    }
    for (long i = i0; i < NQKV_; i += stride) {
        long which = i >> 9, nn = i & 511;
        const float* bb = (which == 0) ? bq : (which == 1) ? bk : bv;
        bqkv[i] = bb[nn];
    }
}

// ------------------------------------------------------------------- GEMM ---
#define GP 40
template <bool OUT_F16>
__global__ __launch_bounds__(256) void gemm_bt(
    const _Float16* __restrict__ A, const _Float16* __restrict__ BT,
    const float* __restrict__ bias, void* __restrict__ Cout,
    int M, int N, int K)
{
    __shared__ _Float16 As[128 * GP];
    __shared__ _Float16 Bs[128 * GP];

    int tid = threadIdx.x;
    int w = tid >> 6, lane = tid & 63, quad = lane >> 4, l16 = lane & 15;
    long row0 = (long)blockIdx.x * 128, col0 = (long)blockIdx.y * 128;
    int wr = (w >> 1) * 64, wc = (w & 1) * 64;

    f4 acc[4][4];
    for (int i = 0; i < 4; i++)
        for (int j = 0; j < 4; j++) acc[i][j] = (f4){0.f, 0.f, 0.f, 0.f};

    int sr = tid >> 1, sc = (tid & 1) * 16;
    for (int k0 = 0; k0 < K; k0 += 32) {
        __syncthreads();
        {
            const h8* ga = (const h8*)(A  + (row0 + sr) * K + k0 + sc);
            const h8* gb = (const h8*)(BT + (col0 + sr) * K + k0 + sc);
            *(h8*)(As + sr * GP + sc)     = ga[0];
            *(h8*)(As + sr * GP + sc + 8) = ga[1];
            *(h8*)(Bs + sr * GP + sc)     = gb[0];
            *(h8*)(Bs + sr * GP + sc + 8) = gb[1];
        }
        __syncthreads();
        h8 af[4], bf[4];
        for (int i = 0; i < 4; i++) af[i] = *(const h8*)(As + (wr + i * 16 + l16) * GP + quad * 8);
        for (int j = 0; j < 4; j++) bf[j] = *(const h8*)(Bs + (wc + j * 16 + l16) * GP + quad * 8);
        for (int i = 0; i < 4; i++)
            for (int j = 0; j < 4; j++)
                acc[i][j] = __builtin_amdgcn_mfma_f32_16x16x32_f16(af[i], bf[j], acc[i][j], 0, 0, 0);
    }
    for (int i = 0; i < 4; i++)
        for (int j = 0; j < 4; j++)
            for (int r = 0; r < 4; r++) {
                long row = row0 + wr + i * 16 + quad * 4 + r;
                long col = col0 + wc + j * 16 + l16;
                float v = acc[i][j][r] + bias[col];
                if (OUT_F16) ((_Float16*)Cout)[row * N + col] = (_Float16)v;
                else         ((float*)Cout)[row * N + col]    = v;
            }
}

// ------------------------------------------------------------ V transpose ---
// vT[b][d][s] = (bf16) qkv[b*4096+s][1024+d]
__global__ __launch_bounds__(256) void transpose_v(const _Float16* __restrict__ qkv,
                                                   __bf16* __restrict__ vT)
{
    __shared__ float tile[32][33];
    int b = blockIdx.z;
    int s0 = blockIdx.x * 32, h0 = blockIdx.y * 32;
    int x = threadIdx.x & 31, y = threadIdx.x >> 5;
    for (int i = 0; i < 4; i++) {
        int s = s0 + y + i * 8;
        tile[y + i * 8][x] = (float)qkv[((long)b * S_ + s) * NQKV_ + 1024 + h0 + x];
    }
    __syncthreads();
    for (int i = 0; i < 4; i++) {
        int h = h0 + y + i * 8;
        vT[((long)b * D_ + h) * S_ + s0 + x] = (__bf16)tile[x][y + i * 8];
    }
}

// -------------------------------------------------------- flash attention ---
// BR=32 rows/block, BC=32 keys/iter, 4 waves, 512 blocks (2/CU).
// Latency-restructured: ONE __syncthreads per iteration.
//   - K double-buffered in LDS; DMA for kt+1 issued BEFORE the score MFMAs of
//     kt, so its flight time is covered by scores+exp (not just PV).
//   - Ps double-buffered (tiny) -> PV(kt) reads and exp(kt+1) writes go to
//     different buffers; the post-PV barrier is deleted.
//   - V fragments loaded global->reg at top of iter, used after the barrier
//     (single buffer, no copies).
//   - QK^T accumulation split into two independent 8-deep MFMA chains.
// Hazards (all separated by exactly one barrier in every wave order):
//   Ks[nxt] DMA-write(kt) vs scores-read(kt-1): B(kt-1) precedes top(kt).
//   Ks[cur] scores-read(kt) vs DMA(kt) issued top(kt-1): drained at B(kt-1).
//   Ps[cur] exp-write(kt) vs PV-read(kt-2) same buffer: B(kt-1) between.
__global__ __launch_bounds__(256, 2) void attn_kernel(const _Float16* __restrict__ qkv,
                                                      const __bf16* __restrict__ vT,
                                                      _Float16* __restrict__ yb)
{
    __shared__ _Float16 Ks[2][BC * KP];     // 2 x 33280 B
    __shared__ __bf16   Ps[2][BR * PP];     // 2 x 2560 B
    __shared__ float    lpart[2][BR];       // 256 B

    const int tid = threadIdx.x;
    const int w = tid >> 6, lane = tid & 63, quad = lane >> 4, l16 = lane & 15;
    const int rs = (w & 1) * 16;            // score row strip
    const int kh = w >> 1;                  // key half (0/1)
    const int b = blockIdx.y;
    const long q0 = (long)blockIdx.x * BR;
    const long rowBase = (long)b * S_;

    const _Float16* kbase = qkv + rowBase * NQKV_ + 512;

    // ---- prologue: stage K tile 0 into Ks[0]
#pragma unroll
    for (int i = 0; i < 8; i++) {
        int r = w * 8 + i;
        gl_lds16(kbase + (long)r * NQKV_ + lane * 8, Ks[0] + r * KP);
    }

    // V fragment base: lane (quad,l16), frag ct: d = w*128+ct*16+l16,
    // keys quad*8..+7 -- 16 contiguous bytes of global vT = the PV B-operand.
    const __bf16* vbase = vT + ((long)b * D_ + w * 128 + l16) * S_ + quad * 8;

    // ---- Q fragments: row q0 + rs + l16, all 512 k (reused all 128 iters)
    h8 Qf[16];
    {
        const _Float16* qrow = qkv + (rowBase + q0 + rs + l16) * NQKV_;
#pragma unroll
        for (int ks = 0; ks < 16; ks++)
            Qf[ks] = *(const h8*)(qrow + ks * 32 + quad * 8);
    }

    f4 O[2][8];
#pragma unroll
    for (int rt = 0; rt < 2; rt++)
#pragma unroll
        for (int ct = 0; ct < 8; ct++) O[rt][ct] = (f4){0.f, 0.f, 0.f, 0.f};
    float lo[4] = {0.f, 0.f, 0.f, 0.f};

    __syncthreads();   // K0 DMA drained + visible

    for (int kt = 0; kt < NIT; kt++) {
        const int cur = kt & 1, nxt = cur ^ 1;

        // ---- issue next K tile DMA immediately (flies during scores+exp)
        if (kt + 1 < NIT) {
            const _Float16* kn = kbase + (long)(kt + 1) * BC * NQKV_;
#pragma unroll
            for (int i = 0; i < 8; i++) {
                int r = w * 8 + i;
                gl_lds16(kn + (long)r * NQKV_ + lane * 8, Ks[nxt] + r * KP);
            }
        }
        // ---- V fragments for THIS iter (used after the barrier)
        b8 vreg[8];
        {
            const __bf16* vs = vbase + (long)kt * BC;
#pragma unroll
            for (int ct = 0; ct < 8; ct++)
                vreg[ct] = *(const b8*)(vs + (long)ct * 16 * S_);
        }

        // ---- scores: 16x16 tile, K=512, two independent 8-deep chains
        f4 S0 = (f4){0.f, 0.f, 0.f, 0.f};
        f4 S1 = (f4){0.f, 0.f, 0.f, 0.f};
        const _Float16* krow = Ks[cur] + (kh * 16 + l16) * KP + quad * 8;
#pragma unroll
        for (int ks = 0; ks < 8; ks++) {
            h8 kb0 = *(const h8*)(krow + ks * 32);
            h8 kb1 = *(const h8*)(krow + (ks + 8) * 32);
            S0 = __builtin_amdgcn_mfma_f32_16x16x32_f16(Qf[ks],     kb0, S0, 0, 0, 0);
            S1 = __builtin_amdgcn_mfma_f32_16x16x32_f16(Qf[ks + 8], kb1, S1, 0, 0, 0);
        }

        // ---- fixed-shift exp; accumulate l from the bf16-rounded P
#pragma unroll
        for (int r = 0; r < 4; r++) {
            float p = exp2f((S0[r] + S1[r]) * L2E - MSH);
            __bf16 pb = (__bf16)p;
            Ps[cur][(rs + quad * 4 + r) * PP + kh * 16 + l16] = pb;
            lo[r] += (float)pb;
        }

        __syncthreads();   // THE barrier: Ps[cur] visible, DMA(kt+1)+vreg drained

        // ---- PV: A = P rows rt*16+l16 (K=32) from LDS, B = V frags from regs
        b8 pa[2];
#pragma unroll
        for (int rt = 0; rt < 2; rt++)
            pa[rt] = *(const b8*)(Ps[cur] + (rt * 16 + l16) * PP + quad * 8);
#pragma unroll
        for (int ct = 0; ct < 8; ct++)
#pragma unroll
            for (int rt = 0; rt < 2; rt++)
                O[rt][ct] = __builtin_amdgcn_mfma_f32_16x16x32_bf16(pa[rt], vreg[ct], O[rt][ct], 0, 0, 0);
    }

    // ---- epilogue: reduce l over the 16 key-columns, publish per half
#pragma unroll
    for (int r = 0; r < 4; r++)
#pragma unroll
        for (int m = 1; m < 16; m <<= 1) lo[r] += __shfl_xor(lo[r], m, 16);
    if (l16 == 0)
        for (int r = 0; r < 4; r++) lpart[kh][rs + quad * 4 + r] = lo[r];
    __syncthreads();

    for (int rt = 0; rt < 2; rt++) {
        f4 l0 = *(const f4*)(&lpart[0][rt * 16 + quad * 4]);
        f4 l1 = *(const f4*)(&lpart[1][rt * 16 + quad * 4]);
        float li[4];
        for (int r = 0; r < 4; r++) li[r] = 1.f / (l0[r] + l1[r]);
        for (int ct = 0; ct < 8; ct++)
            for (int r = 0; r < 4; r++) {
                long row = rowBase + q0 + rt * 16 + quad * 4 + r;
                long col = w * 128 + ct * 16 + l16;
                yb[row * 512 + col] = (_Float16)(O[rt][ct][r] * li[r]);
            }
    }
}

// ----------------------------------------------------------------- launch ---
extern "C" void kernel_launch(void* const* d_in, const int* in_sizes, int n_in,
                              void* d_out, int out_size, void* d_ws, size_t ws_size,
                              hipStream_t stream)
{
    const float* x  = (const float*)d_in[0];
    const float* Wq = (const float*)d_in[1];
    const float* bq = (const float*)d_in[2];
    const float* Wk = (const float*)d_in[3];
    const float* bk = (const float*)d_in[4];
    const float* Wv = (const float*)d_in[5];
    const float* bv = (const float*)d_in[6];
    const float* Wo = (const float*)d_in[7];
    const float* bo = (const float*)d_in[8];
    float* out = (float*)d_out;

    char* ws = (char*)d_ws;
    _Float16* xh    = (_Float16*)(ws);                  // 16 MB
    _Float16* qkv   = (_Float16*)(ws + 16777216);       // 48 MB  [16384][1536]
    __bf16*   vT    = (__bf16*)(ws + 67108864);         // 16 MB  [4][512][4096]
    _Float16* yb    = (_Float16*)(ws + 83886080);       // 16 MB  [16384][512]
    _Float16* wqkvT = (_Float16*)(ws + 100663296);      // 1.5 MB
    _Float16* woT   = (_Float16*)(ws + 102236160);      // 0.5 MB
    float*    bqkv  = (float*)(ws + 102760448);         // 6 KB

    convert_all<<<2048, 256, 0, stream>>>(x, Wq, Wk, Wv, bq, bk, bv, Wo,
                                          xh, wqkvT, woT, bqkv);

    dim3 g1(128, 12);
    gemm_bt<true><<<g1, 256, 0, stream>>>(xh, wqkvT, bqkv, qkv, ROWS_, NQKV_, D_);

    dim3 gt(128, 16, 4);
    transpose_v<<<gt, 256, 0, stream>>>(qkv, vT);

    dim3 ga(128, 4);
    attn_kernel<<<ga, 256, 0, stream>>>(qkv, vT, yb);

    dim3 g2(128, 4);
    gemm_bt<false><<<g2, 256, 0, stream>>>(yb, woT, bo, out, ROWS_, D_, D_);
}

// Round 3
// 347.205 us; speedup vs baseline: 1.3581x; 1.3177x over previous
//
#include <hip/hip_runtime.h>
#include <hip/hip_bf16.h>

typedef _Float16 h8 __attribute__((ext_vector_type(8)));
typedef __bf16   b8 __attribute__((ext_vector_type(8)));
typedef float    f4 __attribute__((ext_vector_type(4)));

#define B_    4
#define S_    4096
#define D_    512
#define ROWS_ (B_ * S_)          // 16384
#define NQKV_ 1536
#define BR    64                 // q-rows per block
#define BC    32                 // keys per iteration
#define KP    520                // K LDS pitch (f16)
#define PP    40                 // P LDS pitch (bf16)
#define NIT   (S_ / BC)          // 128
#define MSH   (30.0f * 1.4426950408889634f)   // fixed softmax shift (log2 units)
#define L2E   1.4426950408889634f

// async global->LDS, 16B per lane; dst is wave-uniform base (+lane*16 implied)
__device__ __forceinline__ void gl_lds16(const void* src, void* dst) {
    __builtin_amdgcn_global_load_lds(
        (const __attribute__((address_space(1))) unsigned int*)src,
        (__attribute__((address_space(3))) unsigned int*)dst, 16, 0, 0);
}

// ---------------------------------------------------------------- convert ---
__global__ __launch_bounds__(256) void convert_all(
    const float* __restrict__ x,
    const float* __restrict__ Wq, const float* __restrict__ Wk, const float* __restrict__ Wv,
    const float* __restrict__ bq, const float* __restrict__ bk, const float* __restrict__ bv,
    const float* __restrict__ Wo,
    _Float16* __restrict__ xh, _Float16* __restrict__ wqkvT, _Float16* __restrict__ woT,
    float* __restrict__ bqkv)
{
    long i0 = (long)blockIdx.x * blockDim.x + threadIdx.x;
    long stride = (long)gridDim.x * blockDim.x;
    const long NX  = (long)ROWS_ * D_;
    const long NW  = (long)D_ * NQKV_;
    const long NWO = (long)D_ * D_;

    for (long i = i0; i < NX; i += stride) xh[i] = (_Float16)x[i];

    for (long i = i0; i < NW; i += stride) {
        long n = i >> 9, k = i & 511;
        long which = n >> 9, nn = n & 511;
        const float* W = (which == 0) ? Wq : (which == 1) ? Wk : Wv;
        wqkvT[i] = (_Float16)W[k * 512 + nn];
    }
    for (long i = i0; i < NWO; i += stride) {
        long n = i >> 9, k = i & 511;
        woT[i] = (_Float16)Wo[k * 512 + n];
    }
    for (long i = i0; i < NQKV_; i += stride) {
        long which = i >> 9, nn = i & 511;
        const float* bb = (which == 0) ? bq : (which == 1) ? bk : bv;
        bqkv[i] = bb[nn];
    }
}

// ------------------------------------------------------------------- GEMM ---
#define GP 40
template <bool OUT_F16>
__global__ __launch_bounds__(256) void gemm_bt(
    const _Float16* __restrict__ A, const _Float16* __restrict__ BT,
    const float* __restrict__ bias, void* __restrict__ Cout,
    int M, int N, int K)
{
    __shared__ _Float16 As[128 * GP];
    __shared__ _Float16 Bs[128 * GP];

    int tid = threadIdx.x;
    int w = tid >> 6, lane = tid & 63, quad = lane >> 4, l16 = lane & 15;
    long row0 = (long)blockIdx.x * 128, col0 = (long)blockIdx.y * 128;
    int wr = (w >> 1) * 64, wc = (w & 1) * 64;

    f4 acc[4][4];
    for (int i = 0; i < 4; i++)
        for (int j = 0; j < 4; j++) acc[i][j] = (f4){0.f, 0.f, 0.f, 0.f};

    int sr = tid >> 1, sc = (tid & 1) * 16;
    for (int k0 = 0; k0 < K; k0 += 32) {
        __syncthreads();
        {
            const h8* ga = (const h8*)(A  + (row0 + sr) * K + k0 + sc);
            const h8* gb = (const h8*)(BT + (col0 + sr) * K + k0 + sc);
            *(h8*)(As + sr * GP + sc)     = ga[0];
            *(h8*)(As + sr * GP + sc + 8) = ga[1];
            *(h8*)(Bs + sr * GP + sc)     = gb[0];
            *(h8*)(Bs + sr * GP + sc + 8) = gb[1];
        }
        __syncthreads();
        h8 af[4], bf[4];
        for (int i = 0; i < 4; i++) af[i] = *(const h8*)(As + (wr + i * 16 + l16) * GP + quad * 8);
        for (int j = 0; j < 4; j++) bf[j] = *(const h8*)(Bs + (wc + j * 16 + l16) * GP + quad * 8);
        for (int i = 0; i < 4; i++)
            for (int j = 0; j < 4; j++)
                acc[i][j] = __builtin_amdgcn_mfma_f32_16x16x32_f16(af[i], bf[j], acc[i][j], 0, 0, 0);
    }
    for (int i = 0; i < 4; i++)
        for (int j = 0; j < 4; j++)
            for (int r = 0; r < 4; r++) {
                long row = row0 + wr + i * 16 + quad * 4 + r;
                long col = col0 + wc + j * 16 + l16;
                float v = acc[i][j][r] + bias[col];
                if (OUT_F16) ((_Float16*)Cout)[row * N + col] = (_Float16)v;
                else         ((float*)Cout)[row * N + col]    = v;
            }
}

// ---------------------------------------------------------------- pack V ---
// vP fragment-major layout: for batch b, key-tile kt (32 keys), d-tile dt
// (16 d), the 16x32 tile is stored as 512 contiguous bf16:
//   vP[(((b*128)+kt)*32+dt)*512 + (q*16+l)*8 + k3] = V[b][kt*32+q*8+k3][dt*16+l]
// so an MFMA B-fragment load is lane*16B off a wave-uniform base.
__global__ __launch_bounds__(256) void pack_v(const _Float16* __restrict__ qkv,
                                              __bf16* __restrict__ vP)
{
    __shared__ _Float16 T[32 * 520];
    int kt = blockIdx.x, b = blockIdx.y;
    int t = threadIdx.x;

    // coalesced load: 32 keys x 512 d (f16) from qkv[.][1024+..]
    const _Float16* src = qkv + ((long)b * S_ + kt * 32 + (t >> 3)) * NQKV_ + 1024;
#pragma unroll
    for (int i = 0; i < 8; i++) {
        int c = (t & 7) + i * 8;                     // chunk 0..63 within row
        *(h8*)(T + (t >> 3) * 520 + c * 8) = *(const h8*)(src + c * 8);
    }
    __syncthreads();

    // coalesced store: 2048 chunks of 8 bf16; chunk c -> dt=c>>6, q=(c>>4)&3, l=c&15
    __bf16* dst = vP + (((long)b * 128 + kt) * 32) * 512;
#pragma unroll
    for (int i = 0; i < 8; i++) {
        int c = t + i * 256;
        int dt = c >> 6, q = (c >> 4) & 3, l = c & 15;
        b8 out;
#pragma unroll
        for (int k3 = 0; k3 < 8; k3++)
            out[k3] = (__bf16)(float)T[(q * 8 + k3) * 520 + dt * 16 + l];
        *(b8*)(dst + (long)c * 8) = out;
    }
}

// -------------------------------------------------------- flash attention ---
// BR=64 rows/block, BC=32 keys/iter, 8 waves (512 thr), 256 blocks (1/CU).
// Halved K/V cache traffic vs BR=32 (each block amortizes the K/V stream over
// 2x the q-rows). V is read from the fragment-packed vP: each wave reads
// contiguous 4KB per iteration (full cache lines, streaming).
// Pipeline: single barrier/iter; K double-buffered in LDS via DMA issued one
// tile ahead at top of iter; Ps double-buffered; V global->reg per iter.
// Wave w (0..7): scores rows rs=(w&3)*16, key half kh=w>>2 (16x16 tile, K=512,
// two 8-deep chains); PV: all 64 rows x d-range w*64..w*64+63 (O[4][4]).
__global__ __launch_bounds__(512, 2) void attn_kernel(const _Float16* __restrict__ qkv,
                                                      const __bf16* __restrict__ vP,
                                                      _Float16* __restrict__ yb)
{
    __shared__ _Float16 Ks[2][BC * KP];     // 2 x 33280 B
    __shared__ __bf16   Ps[2][BR * PP];     // 2 x 5120 B
    __shared__ float    lpart[2][BR];       // 512 B

    const int tid = threadIdx.x;
    const int w = tid >> 6, lane = tid & 63, quad = lane >> 4, l16 = lane & 15;
    const int rs = (w & 3) * 16;            // score row strip
    const int kh = w >> 2;                  // key half (0/1)
    const int b = blockIdx.y;
    const long q0 = (long)blockIdx.x * BR;
    const long rowBase = (long)b * S_;

    const _Float16* kbase = qkv + rowBase * NQKV_ + 512;

    // ---- prologue: stage K tile 0 into Ks[0] (wave stages rows w*4..w*4+3)
#pragma unroll
    for (int i = 0; i < 4; i++) {
        int r = w * 4 + i;
        gl_lds16(kbase + (long)r * NQKV_ + lane * 8, Ks[0] + r * KP);
    }

    // packed-V base: wave w owns d-tiles w*4..w*4+3; per (kt,ct) the fragment
    // is 512 contiguous bf16 at tile index ((b*128+kt)*32 + w*4+ct).
    const __bf16* vpbase = vP + ((long)b * 128 * 32 + w * 4) * 512 + lane * 8;

    // ---- Q fragments: row q0 + rs + l16, all 512 k (reused all 128 iters)
    h8 Qf[16];
    {
        const _Float16* qrow = qkv + (rowBase + q0 + rs + l16) * NQKV_;
#pragma unroll
        for (int ks = 0; ks < 16; ks++)
            Qf[ks] = *(const h8*)(qrow + ks * 32 + quad * 8);
    }

    f4 O[4][4];
#pragma unroll
    for (int rt = 0; rt < 4; rt++)
#pragma unroll
        for (int ct = 0; ct < 4; ct++) O[rt][ct] = (f4){0.f, 0.f, 0.f, 0.f};
    float lo[4] = {0.f, 0.f, 0.f, 0.f};

    __syncthreads();   // K0 DMA drained + visible

    for (int kt = 0; kt < NIT; kt++) {
        const int cur = kt & 1, nxt = cur ^ 1;

        // ---- issue next K tile DMA immediately (flies during scores+exp)
        if (kt + 1 < NIT) {
            const _Float16* kn = kbase + (long)(kt + 1) * BC * NQKV_;
#pragma unroll
            for (int i = 0; i < 4; i++) {
                int r = w * 4 + i;
                gl_lds16(kn + (long)r * NQKV_ + lane * 8, Ks[nxt] + r * KP);
            }
        }
        // ---- V fragments for THIS iter: contiguous 4KB per wave
        b8 vreg[4];
        {
            const __bf16* vs = vpbase + (long)kt * (32 * 512);
#pragma unroll
            for (int ct = 0; ct < 4; ct++)
                vreg[ct] = *(const b8*)(vs + ct * 512);
        }

        // ---- scores: 16x16 tile, K=512, two independent 8-deep chains
        f4 S0 = (f4){0.f, 0.f, 0.f, 0.f};
        f4 S1 = (f4){0.f, 0.f, 0.f, 0.f};
        const _Float16* krow = Ks[cur] + (kh * 16 + l16) * KP + quad * 8;
#pragma unroll
        for (int ks = 0; ks < 8; ks++) {
            h8 kb0 = *(const h8*)(krow + ks * 32);
            h8 kb1 = *(const h8*)(krow + (ks + 8) * 32);
            S0 = __builtin_amdgcn_mfma_f32_16x16x32_f16(Qf[ks],     kb0, S0, 0, 0, 0);
            S1 = __builtin_amdgcn_mfma_f32_16x16x32_f16(Qf[ks + 8], kb1, S1, 0, 0, 0);
        }

        // ---- fixed-shift exp; accumulate l from the bf16-rounded P
#pragma unroll
        for (int r = 0; r < 4; r++) {
            float p = exp2f((S0[r] + S1[r]) * L2E - MSH);
            __bf16 pb = (__bf16)p;
            Ps[cur][(rs + quad * 4 + r) * PP + kh * 16 + l16] = pb;
            lo[r] += (float)pb;
        }

        __syncthreads();   // THE barrier: Ps[cur] visible, DMA(kt+1)+vreg drained

        // ---- PV: A = P rows rt*16+l16 (K=32) from LDS, B = V frags from regs
        b8 pa[4];
#pragma unroll
        for (int rt = 0; rt < 4; rt++)
            pa[rt] = *(const b8*)(Ps[cur] + (rt * 16 + l16) * PP + quad * 8);
#pragma unroll
        for (int ct = 0; ct < 4; ct++)
#pragma unroll
            for (int rt = 0; rt < 4; rt++)
                O[rt][ct] = __builtin_amdgcn_mfma_f32_16x16x32_bf16(pa[rt], vreg[ct], O[rt][ct], 0, 0, 0);
    }

    // ---- epilogue: reduce l over the 16 key-columns, publish per half
#pragma unroll
    for (int r = 0; r < 4; r++)
#pragma unroll
        for (int m = 1; m < 16; m <<= 1) lo[r] += __shfl_xor(lo[r], m, 16);
    if (l16 == 0)
        for (int r = 0; r < 4; r++) lpart[kh][rs + quad * 4 + r] = lo[r];
    __syncthreads();

    for (int rt = 0; rt < 4; rt++) {
        f4 l0 = *(const f4*)(&lpart[0][rt * 16 + quad * 4]);
        f4 l1 = *(const f4*)(&lpart[1][rt * 16 + quad * 4]);
        float li[4];
        for (int r = 0; r < 4; r++) li[r] = 1.f / (l0[r] + l1[r]);
        for (int ct = 0; ct < 4; ct++)
            for (int r = 0; r < 4; r++) {
                long row = rowBase + q0 + rt * 16 + quad * 4 + r;
                long col = w * 64 + ct * 16 + l16;
                yb[row * 512 + col] = (_Float16)(O[rt][ct][r] * li[r]);
            }
    }
}

// ----------------------------------------------------------------- launch ---
extern "C" void kernel_launch(void* const* d_in, const int* in_sizes, int n_in,
                              void* d_out, int out_size, void* d_ws, size_t ws_size,
                              hipStream_t stream)
{
    const float* x  = (const float*)d_in[0];
    const float* Wq = (const float*)d_in[1];
    const float* bq = (const float*)d_in[2];
    const float* Wk = (const float*)d_in[3];
    const float* bk = (const float*)d_in[4];
    const float* Wv = (const float*)d_in[5];
    const float* bv = (const float*)d_in[6];
    const float* Wo = (const float*)d_in[7];
    const float* bo = (const float*)d_in[8];
    float* out = (float*)d_out;

    char* ws = (char*)d_ws;
    _Float16* xh    = (_Float16*)(ws);                  // 16 MB
    _Float16* qkv   = (_Float16*)(ws + 16777216);       // 48 MB  [16384][1536]
    __bf16*   vP    = (__bf16*)(ws + 67108864);         // 16 MB  packed V
    _Float16* yb    = (_Float16*)(ws + 83886080);       // 16 MB  [16384][512]
    _Float16* wqkvT = (_Float16*)(ws + 100663296);      // 1.5 MB
    _Float16* woT   = (_Float16*)(ws + 102236160);      // 0.5 MB
    float*    bqkv  = (float*)(ws + 102760448);         // 6 KB

    convert_all<<<2048, 256, 0, stream>>>(x, Wq, Wk, Wv, bq, bk, bv, Wo,
                                          xh, wqkvT, woT, bqkv);

    dim3 g1(128, 12);
    gemm_bt<true><<<g1, 256, 0, stream>>>(xh, wqkvT, bqkv, qkv, ROWS_, NQKV_, D_);

    dim3 gp(128, 4);
    pack_v<<<gp, 256, 0, stream>>>(qkv, vP);

    dim3 ga(64, 4);
    attn_kernel<<<ga, 512, 0, stream>>>(qkv, vP, yb);

    dim3 g2(128, 4);
    gemm_bt<false><<<g2, 256, 0, stream>>>(yb, woT, bo, out, ROWS_, D_, D_);
}

// Round 4
// 340.108 us; speedup vs baseline: 1.3865x; 1.0209x over previous
//
#include <hip/hip_runtime.h>
#include <hip/hip_bf16.h>

typedef _Float16 h8 __attribute__((ext_vector_type(8)));
typedef __bf16   b8 __attribute__((ext_vector_type(8)));
typedef float    f4 __attribute__((ext_vector_type(4)));

#define B_    4
#define S_    4096
#define D_    512
#define ROWS_ (B_ * S_)          // 16384
#define NQKV_ 1536
#define BR    64                 // q-rows per block
#define BC    32                 // keys per iteration
#define KP    520                // K LDS pitch (f16)
#define PP    40                 // P LDS pitch (bf16)
#define NIT   (S_ / BC)          // 128
#define KTILE (BC * KP)
#define MSH   (30.0f * 1.4426950408889634f)   // fixed softmax shift (log2 units)
#define L2E   1.4426950408889634f

// async global->LDS, 16B per lane; dst is wave-uniform base (+lane*16 implied)
__device__ __forceinline__ void gl_lds16(const void* src, void* dst) {
    __builtin_amdgcn_global_load_lds(
        (const __attribute__((address_space(1))) unsigned int*)src,
        (__attribute__((address_space(3))) unsigned int*)dst, 16, 0, 0);
}

// ---------------------------------------------------------------- convert ---
__global__ __launch_bounds__(256) void convert_all(
    const float* __restrict__ x,
    const float* __restrict__ Wq, const float* __restrict__ Wk, const float* __restrict__ Wv,
    const float* __restrict__ bq, const float* __restrict__ bk, const float* __restrict__ bv,
    const float* __restrict__ Wo,
    _Float16* __restrict__ xh, _Float16* __restrict__ wqkvT, _Float16* __restrict__ woT,
    float* __restrict__ bqkv)
{
    long i0 = (long)blockIdx.x * blockDim.x + threadIdx.x;
    long stride = (long)gridDim.x * blockDim.x;
    const long NX  = (long)ROWS_ * D_;
    const long NW  = (long)D_ * NQKV_;
    const long NWO = (long)D_ * D_;

    for (long i = i0; i < NX; i += stride) xh[i] = (_Float16)x[i];

    for (long i = i0; i < NW; i += stride) {
        long n = i >> 9, k = i & 511;
        long which = n >> 9, nn = n & 511;
        const float* W = (which == 0) ? Wq : (which == 1) ? Wk : Wv;
        wqkvT[i] = (_Float16)W[k * 512 + nn];
    }
    for (long i = i0; i < NWO; i += stride) {
        long n = i >> 9, k = i & 511;
        woT[i] = (_Float16)Wo[k * 512 + n];
    }
    for (long i = i0; i < NQKV_; i += stride) {
        long which = i >> 9, nn = i & 511;
        const float* bb = (which == 0) ? bq : (which == 1) ? bk : bv;
        bqkv[i] = bb[nn];
    }
}

// ------------------------------------------------------------------- GEMM ---
#define GP 40
template <bool OUT_F16>
__global__ __launch_bounds__(256) void gemm_bt(
    const _Float16* __restrict__ A, const _Float16* __restrict__ BT,
    const float* __restrict__ bias, void* __restrict__ Cout,
    int M, int N, int K)
{
    __shared__ _Float16 As[128 * GP];
    __shared__ _Float16 Bs[128 * GP];

    int tid = threadIdx.x;
    int w = tid >> 6, lane = tid & 63, quad = lane >> 4, l16 = lane & 15;
    long row0 = (long)blockIdx.x * 128, col0 = (long)blockIdx.y * 128;
    int wr = (w >> 1) * 64, wc = (w & 1) * 64;

    f4 acc[4][4];
    for (int i = 0; i < 4; i++)
        for (int j = 0; j < 4; j++) acc[i][j] = (f4){0.f, 0.f, 0.f, 0.f};

    int sr = tid >> 1, sc = (tid & 1) * 16;
    for (int k0 = 0; k0 < K; k0 += 32) {
        __syncthreads();
        {
            const h8* ga = (const h8*)(A  + (row0 + sr) * K + k0 + sc);
            const h8* gb = (const h8*)(BT + (col0 + sr) * K + k0 + sc);
            *(h8*)(As + sr * GP + sc)     = ga[0];
            *(h8*)(As + sr * GP + sc + 8) = ga[1];
            *(h8*)(Bs + sr * GP + sc)     = gb[0];
            *(h8*)(Bs + sr * GP + sc + 8) = gb[1];
        }
        __syncthreads();
        h8 af[4], bf[4];
        for (int i = 0; i < 4; i++) af[i] = *(const h8*)(As + (wr + i * 16 + l16) * GP + quad * 8);
        for (int j = 0; j < 4; j++) bf[j] = *(const h8*)(Bs + (wc + j * 16 + l16) * GP + quad * 8);
        for (int i = 0; i < 4; i++)
            for (int j = 0; j < 4; j++)
                acc[i][j] = __builtin_amdgcn_mfma_f32_16x16x32_f16(af[i], bf[j], acc[i][j], 0, 0, 0);
    }
    for (int i = 0; i < 4; i++)
        for (int j = 0; j < 4; j++)
            for (int r = 0; r < 4; r++) {
                long row = row0 + wr + i * 16 + quad * 4 + r;
                long col = col0 + wc + j * 16 + l16;
                float v = acc[i][j][r] + bias[col];
                if (OUT_F16) ((_Float16*)Cout)[row * N + col] = (_Float16)v;
                else         ((float*)Cout)[row * N + col]    = v;
            }
}

// ---------------------------------------------------------------- pack V ---
// vP fragment-major layout: for batch b, key-tile kt (32 keys), d-tile dt
// (16 d), the 16x32 tile is stored as 512 contiguous bf16:
//   vP[(((b*128)+kt)*32+dt)*512 + (q*16+l)*8 + k3] = V[b][kt*32+q*8+k3][dt*16+l]
// so an MFMA B-fragment load is lane*16B off a wave-uniform base.
__global__ __launch_bounds__(256) void pack_v(const _Float16* __restrict__ qkv,
                                              __bf16* __restrict__ vP)
{
    __shared__ _Float16 T[32 * 520];
    int kt = blockIdx.x, b = blockIdx.y;
    int t = threadIdx.x;

    // coalesced load: 32 keys x 512 d (f16) from qkv[.][1024+..]
    const _Float16* src = qkv + ((long)b * S_ + kt * 32 + (t >> 3)) * NQKV_ + 1024;
#pragma unroll
    for (int i = 0; i < 8; i++) {
        int c = (t & 7) + i * 8;                     // chunk 0..63 within row
        *(h8*)(T + (t >> 3) * 520 + c * 8) = *(const h8*)(src + c * 8);
    }
    __syncthreads();

    // coalesced store: 2048 chunks of 8 bf16; chunk c -> dt=c>>6, q=(c>>4)&3, l=c&15
    __bf16* dst = vP + (((long)b * 128 + kt) * 32) * 512;
#pragma unroll
    for (int i = 0; i < 8; i++) {
        int c = t + i * 256;
        int dt = c >> 6, q = (c >> 4) & 3, l = c & 15;
        b8 out;
#pragma unroll
        for (int k3 = 0; k3 < 8; k3++)
            out[k3] = (__bf16)(float)T[(q * 8 + k3) * 520 + dt * 16 + l];
        *(b8*)(dst + (long)c * 8) = out;
    }
}

// -------------------------------------------------------- flash attention ---
// BR=64, BC=32, 8 waves (512 thr), 256 blocks (1/CU).
// Counted-vmcnt pipeline (T4): raw s_barrier, NEVER vmcnt(0) in the loop.
//   - K: 4 LDS buffers, DMA issued 2 tiles ahead (cover ~1.7 iter).
//   - V: global->reg from packed vP, 1 tile ahead, vA/vB ping-pong via 2x
//     unroll (cover ~1.6 iter).
//   - Issue order per iter: V(kt+1) x4, then DMA(kt+2) x4  (8 vmem ops).
//     Invariant: vmcnt(8) at barrier(kt) retires all but the 8 newest ops
//     => DMA(kt+1) complete before scores(kt+1) reads it (in-order vmcnt
//     retirement), independent of scheduler reorder within the region.
//   - lgkmcnt(0) before s_barrier publishes Ps (double-buffered).
// Hazards: Ks buf (kt+2)&3 WAR vs scores(kt-2) reads: 2 barriers apart. Ps
// WAR: write(kt+2) vs PV-read(kt): PV(kt) MFMAs issue before barrier(kt+1).
__global__ __launch_bounds__(512, 2) void attn_kernel(const _Float16* __restrict__ qkv,
                                                      const __bf16* __restrict__ vP,
                                                      _Float16* __restrict__ yb)
{
    __shared__ _Float16 Ks[4 * KTILE];      // 133120 B
    __shared__ __bf16   Ps[2 * BR * PP];    // 10240 B
    __shared__ float    lpart[2][BR];       // 512 B

    const int tid = threadIdx.x;
    const int w = tid >> 6, lane = tid & 63, quad = lane >> 4, l16 = lane & 15;
    const int rs = (w & 3) * 16;            // score row strip
    const int kh = w >> 2;                  // key half (0/1)
    const int b = blockIdx.y;
    const long q0 = (long)blockIdx.x * BR;
    const long rowBase = (long)b * S_;

    const _Float16* kbase = qkv + rowBase * NQKV_ + 512;
    const __bf16* vpbase = vP + ((long)b * 128 * 32 + w * 4) * 512 + lane * 8;

    // ---- Q fragments FIRST (oldest vmem; drained by scores(0) auto-wait)
    h8 Qf[16];
    {
        const _Float16* qrow = qkv + (rowBase + q0 + rs + l16) * NQKV_;
#pragma unroll
        for (int ks = 0; ks < 16; ks++)
            Qf[ks] = *(const h8*)(qrow + ks * 32 + quad * 8);
    }

    // ---- prologue: DMA K tiles 0,1; then V(0) into vA
#pragma unroll
    for (int t = 0; t < 2; t++)
#pragma unroll
        for (int i = 0; i < 4; i++) {
            int r = w * 4 + i;
            gl_lds16(kbase + (long)(t * BC + r) * NQKV_ + lane * 8,
                     Ks + t * KTILE + r * KP);
        }
    b8 vA[4], vB[4];
#pragma unroll
    for (int ct = 0; ct < 4; ct++)
        vA[ct] = *(const b8*)(vpbase + ct * 512);

    f4 O[4][4];
#pragma unroll
    for (int rt = 0; rt < 4; rt++)
#pragma unroll
        for (int ct = 0; ct < 4; ct++) O[rt][ct] = (f4){0.f, 0.f, 0.f, 0.f};
    float lo[4] = {0.f, 0.f, 0.f, 0.f};

    __builtin_amdgcn_sched_barrier(0);
    asm volatile("s_waitcnt vmcnt(8)");     // DMA(0) done; DMA(1)+V(0) in flight
    __builtin_amdgcn_s_barrier();
    __builtin_amdgcn_sched_barrier(0);

#define ATTN_BODY(KT, VUSE, VLOAD)                                              \
  {                                                                             \
    const int kt_ = (KT);                                                       \
    /* V(kt+1) loads first, then DMA(kt+2): 8 vmem ops per steady iter */       \
    if (kt_ + 1 < NIT) {                                                        \
      const __bf16* vs = vpbase + (long)(kt_ + 1) * (32 * 512);                 \
      _Pragma("unroll")                                                         \
      for (int ct = 0; ct < 4; ct++)                                            \
        VLOAD[ct] = *(const b8*)(vs + ct * 512);                                \
    }                                                                           \
    if (kt_ + 2 < NIT) {                                                        \
      const _Float16* kn = kbase + (long)(kt_ + 2) * BC * NQKV_;                \
      _Float16* kd = Ks + ((kt_ + 2) & 3) * KTILE;                              \
      _Pragma("unroll")                                                         \
      for (int i = 0; i < 4; i++) {                                             \
        int r = w * 4 + i;                                                      \
        gl_lds16(kn + (long)r * NQKV_ + lane * 8, kd + r * KP);                 \
      }                                                                         \
    }                                                                           \
    /* scores: 16x16 tile, K=512, two independent 8-deep chains */              \
    f4 S0 = (f4){0.f, 0.f, 0.f, 0.f};                                           \
    f4 S1 = (f4){0.f, 0.f, 0.f, 0.f};                                           \
    const _Float16* krow = Ks + (kt_ & 3) * KTILE + (kh * 16 + l16) * KP + quad * 8; \
    _Pragma("unroll")                                                           \
    for (int ks = 0; ks < 8; ks++) {                                            \
      h8 kb0 = *(const h8*)(krow + ks * 32);                                    \
      h8 kb1 = *(const h8*)(krow + (ks + 8) * 32);                              \
      S0 = __builtin_amdgcn_mfma_f32_16x16x32_f16(Qf[ks],     kb0, S0, 0, 0, 0);\
      S1 = __builtin_amdgcn_mfma_f32_16x16x32_f16(Qf[ks + 8], kb1, S1, 0, 0, 0);\
    }                                                                           \
    __bf16* ps = Ps + (kt_ & 1) * (BR * PP);                                    \
    _Pragma("unroll")                                                           \
    for (int r = 0; r < 4; r++) {                                               \
      float p = exp2f((S0[r] + S1[r]) * L2E - MSH);                             \
      __bf16 pb = (__bf16)p;                                                    \
      ps[(rs + quad * 4 + r) * PP + kh * 16 + l16] = pb;                        \
      lo[r] += (float)pb;                                                       \
    }                                                                           \
    __builtin_amdgcn_sched_barrier(0);                                          \
    if (kt_ < NIT - 2)       asm volatile("s_waitcnt vmcnt(8)");                \
    else if (kt_ == NIT - 2) asm volatile("s_waitcnt vmcnt(4)");                \
    asm volatile("s_waitcnt lgkmcnt(0)");                                       \
    __builtin_amdgcn_s_barrier();                                               \
    __builtin_amdgcn_sched_barrier(0);                                          \
    /* PV: A = P rows rt*16+l16 (K=32) from LDS, B = V frags from regs */       \
    b8 pa[4];                                                                   \
    _Pragma("unroll")                                                           \
    for (int rt = 0; rt < 4; rt++)                                              \
      pa[rt] = *(const b8*)(ps + (rt * 16 + l16) * PP + quad * 8);              \
    _Pragma("unroll")                                                           \
    for (int ct = 0; ct < 4; ct++)                                              \
      _Pragma("unroll")                                                         \
      for (int rt = 0; rt < 4; rt++)                                            \
        O[rt][ct] = __builtin_amdgcn_mfma_f32_16x16x32_bf16(pa[rt], VUSE[ct], O[rt][ct], 0, 0, 0); \
  }

    for (int kt = 0; kt < NIT; kt += 2) {
        ATTN_BODY(kt,     vA, vB);
        ATTN_BODY(kt + 1, vB, vA);
    }
#undef ATTN_BODY

    // ---- epilogue: reduce l over the 16 key-columns, publish per half
#pragma unroll
    for (int r = 0; r < 4; r++)
#pragma unroll
        for (int m = 1; m < 16; m <<= 1) lo[r] += __shfl_xor(lo[r], m, 16);
    if (l16 == 0)
        for (int r = 0; r < 4; r++) lpart[kh][rs + quad * 4 + r] = lo[r];
    __syncthreads();

    for (int rt = 0; rt < 4; rt++) {
        f4 l0 = *(const f4*)(&lpart[0][rt * 16 + quad * 4]);
        f4 l1 = *(const f4*)(&lpart[1][rt * 16 + quad * 4]);
        float li[4];
        for (int r = 0; r < 4; r++) li[r] = 1.f / (l0[r] + l1[r]);
        for (int ct = 0; ct < 4; ct++)
            for (int r = 0; r < 4; r++) {
                long row = rowBase + q0 + rt * 16 + quad * 4 + r;
                long col = w * 64 + ct * 16 + l16;
                yb[row * 512 + col] = (_Float16)(O[rt][ct][r] * li[r]);
            }
    }
}

// ----------------------------------------------------------------- launch ---
extern "C" void kernel_launch(void* const* d_in, const int* in_sizes, int n_in,
                              void* d_out, int out_size, void* d_ws, size_t ws_size,
                              hipStream_t stream)
{
    const float* x  = (const float*)d_in[0];
    const float* Wq = (const float*)d_in[1];
    const float* bq = (const float*)d_in[2];
    const float* Wk = (const float*)d_in[3];
    const float* bk = (const float*)d_in[4];
    const float* Wv = (const float*)d_in[5];
    const float* bv = (const float*)d_in[6];
    const float* Wo = (const float*)d_in[7];
    const float* bo = (const float*)d_in[8];
    float* out = (float*)d_out;

    char* ws = (char*)d_ws;
    _Float16* xh    = (_Float16*)(ws);                  // 16 MB
    _Float16* qkv   = (_Float16*)(ws + 16777216);       // 48 MB  [16384][1536]
    __bf16*   vP    = (__bf16*)(ws + 67108864);         // 16 MB  packed V
    _Float16* yb    = (_Float16*)(ws + 83886080);       // 16 MB  [16384][512]
    _Float16* wqkvT = (_Float16*)(ws + 100663296);      // 1.5 MB
    _Float16* woT   = (_Float16*)(ws + 102236160);      // 0.5 MB
    float*    bqkv  = (float*)(ws + 102760448);         // 6 KB

    convert_all<<<2048, 256, 0, stream>>>(x, Wq, Wk, Wv, bq, bk, bv, Wo,
                                          xh, wqkvT, woT, bqkv);

    dim3 g1(128, 12);
    gemm_bt<true><<<g1, 256, 0, stream>>>(xh, wqkvT, bqkv, qkv, ROWS_, NQKV_, D_);

    dim3 gp(128, 4);
    pack_v<<<gp, 256, 0, stream>>>(qkv, vP);

    dim3 ga(64, 4);
    attn_kernel<<<ga, 512, 0, stream>>>(qkv, vP, yb);

    dim3 g2(128, 4);
    gemm_bt<false><<<g2, 256, 0, stream>>>(yb, woT, bo, out, ROWS_, D_, D_);
}